// Round 2
// baseline (241.878 us; speedup 1.0000x reference)
//
#include <hip/hip_runtime.h>
#include <hip/hip_bf16.h>

#define EPS 1e-8f
#define LDH 72  // padded row stride (halves) for 64x64 fp16 LDS tiles

typedef _Float16 half8 __attribute__((ext_vector_type(8)));
typedef float f32x4 __attribute__((ext_vector_type(4)));

__device__ __forceinline__ float softplus_f(float x) {
    return fmaxf(x, 0.f) + log1pf(expf(-fabsf(x)));
}

struct NmfLds {
    _Float16 A_rm[64 * LDH];
    _Float16 A_cm[64 * LDH];
    _Float16 U_rm[64 * LDH];
    _Float16 U_cm[64 * LDH];
    _Float16 V_rm[64 * LDH];
    _Float16 V_cm[64 * LDH];
    _Float16 WZ[64 * LDH];
    float vsum[64];
};

// C = L @ R for 64x64 fp16 tiles. L: MxK row-major. R passed as R^T row-major (NxK).
// Wave computes rows [wave*16, wave*16+16) x all 64 cols into acc[4] (col tiles).
__device__ __forceinline__ void mm64(const _Float16* L, const _Float16* R,
                                     int wave, int lr, int lk, f32x4 acc[4]) {
#pragma unroll
    for (int k = 0; k < 2; ++k) {
        half8 a = *(const half8*)(L + (wave * 16 + lr) * LDH + k * 32 + lk * 8);
#pragma unroll
        for (int ct = 0; ct < 4; ++ct) {
            half8 bf = *(const half8*)(R + (ct * 16 + lr) * LDH + k * 32 + lk * 8);
            acc[ct] = __builtin_amdgcn_mfma_f32_16x16x32_f16(a, bf, acc[ct], 0, 0, 0);
        }
    }
}

// store acc (C row-major fp16) into a 64xLDH LDS buffer
__device__ __forceinline__ void store_acc(_Float16* B, int wave, int lr, int lk,
                                          const f32x4 acc[4]) {
#pragma unroll
    for (int t = 0; t < 4; ++t)
#pragma unroll
        for (int q = 0; q < 4; ++q)
            B[(wave * 16 + lk * 4 + q) * LDH + t * 16 + lr] = (_Float16)acc[t][q];
}

__global__ __launch_bounds__(256, 2) void nmf_kernel(const float* __restrict__ Ag,
                                                     const float* __restrict__ U0,
                                                     const float* __restrict__ V0,
                                                     float* __restrict__ out,
                                                     float* __restrict__ ws) {
    __shared__ NmfLds S;
    const int b = blockIdx.x;
    const int tid = threadIdx.x;
    const int wave = tid >> 6;
    const int lane = tid & 63;
    const int lr = lane & 15;
    const int lk = lane >> 4;

    const float* Ab = Ag + (size_t)b * 4096;
    const float* Ub = U0 + (size_t)b * 4096;
    const float* Vb = V0 + (size_t)b * 4096;

    float Ureg[16], Vreg[16];

#pragma unroll
    for (int q = 0; q < 4; ++q) {
        const int r = wave * 16 + lk * 4 + q;
#pragma unroll
        for (int t = 0; t < 4; ++t) {
            const int c = t * 16 + lr;
            float a = Ab[r * 64 + c];
            S.A_rm[r * LDH + c] = (_Float16)a;
            S.A_cm[c * LDH + r] = (_Float16)a;
            float u = softplus_f(Ub[r * 64 + c]);
            Ureg[q * 4 + t] = u;
            S.U_rm[r * LDH + c] = (_Float16)u;
            S.U_cm[c * LDH + r] = (_Float16)u;
            float v = softplus_f(Vb[r * 64 + c]);
            Vreg[q * 4 + t] = v;
            S.V_rm[r * LDH + c] = (_Float16)v;
            S.V_cm[c * LDH + r] = (_Float16)v;
        }
    }
    __syncthreads();

    const f32x4 zero4 = {0.f, 0.f, 0.f, 0.f};

    for (int it = 0; it < 10; ++it) {
        // P1: T1 = U^T A   (L = U^T rm = U_cm ; R = A -> R^T rm = A_cm)
        f32x4 T1[4] = {zero4, zero4, zero4, zero4};
        mm64(S.U_cm, S.A_cm, wave, lr, lk, T1);
        // P2: W = U^T U    (L = U_cm ; R^T rm = U_cm)
        {
            f32x4 W[4] = {zero4, zero4, zero4, zero4};
            mm64(S.U_cm, S.U_cm, wave, lr, lk, W);
            store_acc(S.WZ, wave, lr, lk, W);
        }
        __syncthreads();  // b1: WZ ready
        // P3: WV = W @ V   (L = WZ ; R^T rm = V_cm)
        f32x4 WV[4] = {zero4, zero4, zero4, zero4};
        mm64(S.WZ, S.V_cm, wave, lr, lk, WV);
        __syncthreads();  // b2: all reads of old V done
        // P4: V = V * T1 / (WV + eps)
#pragma unroll
        for (int q = 0; q < 4; ++q) {
            const int r = wave * 16 + lk * 4 + q;
#pragma unroll
            for (int t = 0; t < 4; ++t) {
                const int c = t * 16 + lr;
                float v = Vreg[q * 4 + t] * T1[t][q] / (WV[t][q] + EPS);
                Vreg[q * 4 + t] = v;
                S.V_rm[r * LDH + c] = (_Float16)v;
                S.V_cm[c * LDH + r] = (_Float16)v;
            }
        }
        __syncthreads();  // b3: new V visible
        // P5: T2 = A @ V^T (L = A_rm ; R = V^T -> R^T rm = V_rm)
        f32x4 T2[4] = {zero4, zero4, zero4, zero4};
        mm64(S.A_rm, S.V_rm, wave, lr, lk, T2);
        // P6: Z = U @ V    (L = U_rm ; R^T rm = V_cm)
        {
            f32x4 Z[4] = {zero4, zero4, zero4, zero4};
            mm64(S.U_rm, S.V_cm, wave, lr, lk, Z);
            store_acc(S.WZ, wave, lr, lk, Z);
        }
        __syncthreads();  // b4: WZ ready, all old-U reads done
        // P7: ZVT = Z @ V^T
        f32x4 ZV[4] = {zero4, zero4, zero4, zero4};
        mm64(S.WZ, S.V_rm, wave, lr, lk, ZV);
        // P8: U = U * T2 / (ZVT + eps)
#pragma unroll
        for (int q = 0; q < 4; ++q) {
            const int r = wave * 16 + lk * 4 + q;
#pragma unroll
            for (int t = 0; t < 4; ++t) {
                const int c = t * 16 + lr;
                float u = Ureg[q * 4 + t] * T2[t][q] / (ZV[t][q] + EPS);
                Ureg[q * 4 + t] = u;
                S.U_rm[r * LDH + c] = (_Float16)u;
                S.U_cm[c * LDH + r] = (_Float16)u;
            }
        }
        __syncthreads();  // b5: next iter reads new U
    }

    // outputs: U at o2, V at o3
    float* Uout = out + 8650752 + (size_t)b * 4096;
    float* Vout = out + 17039360 + (size_t)b * 4096;
#pragma unroll
    for (int q = 0; q < 4; ++q) {
        const int r = wave * 16 + lk * 4 + q;
#pragma unroll
        for (int t = 0; t < 4; ++t) {
            const int c = t * 16 + lr;
            Uout[r * 64 + c] = Ureg[q * 4 + t];
            Vout[r * 64 + c] = Vreg[q * 4 + t];
        }
    }

    // vsum[r] = sum_j V[r][j]
#pragma unroll
    for (int q = 0; q < 4; ++q) {
        float p = Vreg[q * 4 + 0] + Vreg[q * 4 + 1] + Vreg[q * 4 + 2] + Vreg[q * 4 + 3];
        p += __shfl_xor(p, 1);
        p += __shfl_xor(p, 2);
        p += __shfl_xor(p, 4);
        p += __shfl_xor(p, 8);
        if (lr == 0) S.vsum[wave * 16 + lk * 4 + q] = p;
    }
    __syncthreads();
    // rs[r] = sum_k U[r][k] * vsum[k]  -> ws[b*64 + r]
#pragma unroll
    for (int q = 0; q < 4; ++q) {
        float p = 0.f;
#pragma unroll
        for (int t = 0; t < 4; ++t) p += Ureg[q * 4 + t] * S.vsum[t * 16 + lr];
        p += __shfl_xor(p, 1);
        p += __shfl_xor(p, 2);
        p += __shfl_xor(p, 4);
        p += __shfl_xor(p, 8);
        if (lr == 0) ws[(size_t)b * 64 + wave * 16 + lk * 4 + q] = p;
    }
}

__global__ __launch_bounds__(256) void xp_kernel(const float* __restrict__ Xg,
                                                 const float* __restrict__ xn,
                                                 float* __restrict__ out,
                                                 float* __restrict__ ws) {
    __shared__ float X[128 * 65];
    __shared__ float xnew[128];
    __shared__ float red[256];
    __shared__ float tbuf[64];
    __shared__ float xp[128];
    const int b = blockIdx.x, tid = threadIdx.x;
    const float* Xb = Xg + (size_t)b * 8192;

    for (int idx = tid; idx < 2048; idx += 256) {
        float4 v = ((const float4*)Xb)[idx];
        int d = idx >> 4, n = (idx * 4) & 63;
        X[d * 65 + n + 0] = v.x;
        X[d * 65 + n + 1] = v.y;
        X[d * 65 + n + 2] = v.z;
        X[d * 65 + n + 3] = v.w;
    }
    if (tid < 32) {
        float4 v = ((const float4*)(xn + (size_t)b * 128))[tid];
        xnew[tid * 4 + 0] = v.x;
        xnew[tid * 4 + 1] = v.y;
        xnew[tid * 4 + 2] = v.z;
        xnew[tid * 4 + 3] = v.w;
    }
    __syncthreads();
    // t[n] = sum_d xnew[d] * X[d][n]
    {
        const int n = tid & 63, g = tid >> 6;
        float p = 0.f;
        for (int d = g * 32; d < g * 32 + 32; ++d) p += xnew[d] * X[d * 65 + n];
        red[g * 64 + n] = p;
    }
    __syncthreads();
    if (tid < 64) tbuf[tid] = red[tid] + red[64 + tid] + red[128 + tid] + red[192 + tid];
    __syncthreads();
    // xp[d] = sum_n X[d][n] * t[n]
    {
        const int d = tid & 127, h = tid >> 7;
        float p = 0.f;
        for (int n = h * 32; n < h * 32 + 32; ++n) p += X[d * 65 + n] * tbuf[n];
        red[h * 128 + d] = p;
    }
    __syncthreads();
    if (tid < 128) {
        float v = red[tid] + red[128 + tid];
        xp[tid] = v;
        out[8388608 + (size_t)b * 128 + tid] = v;
    }
    __syncthreads();
    // s[n] = sum_d xp[d] * X[d][n]
    {
        const int n = tid & 63, g = tid >> 6;
        float p = 0.f;
        for (int d = g * 32; d < g * 32 + 32; ++d) p += xp[d] * X[d * 65 + n];
        red[g * 64 + n] = p;
    }
    __syncthreads();
    if (tid < 64)
        ws[131072 + (size_t)b * 64 + tid] =
            red[tid] + red[64 + tid] + red[128 + tid] + red[192 + tid];
}

__global__ __launch_bounds__(256) void fuse_kernel(const float* __restrict__ ws,
                                                   float* __restrict__ out) {
    __shared__ float g[64];
    __shared__ float rs[64];
    __shared__ float gmax_s;
    const int b = blockIdx.x, tid = threadIdx.x;
    if (tid < 64) {
        float s = ws[131072 + (size_t)b * 64 + tid];
        g[tid] = s * s * 0.088388347648318447f;  // 1/sqrt(128)
        rs[tid] = ws[(size_t)b * 64 + tid];
    }
    __syncthreads();
    if (tid < 64) {
        float m = g[tid];
#pragma unroll
        for (int o = 1; o < 64; o <<= 1) m = fmaxf(m, __shfl_xor(m, o));
        if (tid == 0) gmax_s = m;
    }
    __syncthreads();
    const float gmax = gmax_s;
    const int i = tid >> 2, part = tid & 3;
    const float r = rs[i];
    float e[16];
    float sum = 0.f;
#pragma unroll
    for (int j = 0; j < 16; ++j) {
        e[j] = expf(r * (g[part * 16 + j] - gmax));
        sum += e[j];
    }
    sum += __shfl_xor(sum, 1);
    sum += __shfl_xor(sum, 2);
    const float inv = 1.f / sum;
    float* o = out + (size_t)b * 4096 + i * 64 + part * 16;
#pragma unroll
    for (int j = 0; j < 16; j += 4) {
        float4 v = {e[j] * inv, e[j + 1] * inv, e[j + 2] * inv, e[j + 3] * inv};
        ((float4*)o)[j >> 2] = v;
    }
}

extern "C" void kernel_launch(void* const* d_in, const int* in_sizes, int n_in,
                              void* d_out, int out_size, void* d_ws, size_t ws_size,
                              hipStream_t stream) {
    (void)in_sizes; (void)n_in; (void)out_size; (void)ws_size;
    const float* Ag = (const float*)d_in[0];
    const float* Xg = (const float*)d_in[1];
    const float* xn = (const float*)d_in[2];
    const float* U0 = (const float*)d_in[3];
    const float* V0 = (const float*)d_in[4];
    float* out = (float*)d_out;
    float* ws = (float*)d_ws;

    hipLaunchKernelGGL(nmf_kernel, dim3(2048), dim3(256), 0, stream, Ag, U0, V0, out, ws);
    hipLaunchKernelGGL(xp_kernel, dim3(2048), dim3(256), 0, stream, Xg, xn, out, ws);
    hipLaunchKernelGGL(fuse_kernel, dim3(2048), dim3(256), 0, stream, ws, out);
}

// Round 3
// 167.691 us; speedup vs baseline: 1.4424x; 1.4424x over previous
//
#include <hip/hip_runtime.h>
#include <hip/hip_bf16.h>

#define EPS 1e-8f
#define LDH 72  // padded row stride (halves): 144B rows, 16B-aligned, bank-stride 4

typedef _Float16 half8 __attribute__((ext_vector_type(8)));
typedef _Float16 half4 __attribute__((ext_vector_type(4)));
typedef float f32x4 __attribute__((ext_vector_type(4)));

__device__ __forceinline__ float softplus_f(float x) {
    return fmaxf(x, 0.f) + log1pf(expf(-fabsf(x)));
}

struct Frag {  // one 16-row strip of a 64x64 fp16 matrix: rows i*16+lr, k 0..63
    half8 h0, h1;
};

__device__ __forceinline__ Frag load_frag(const _Float16* B, int i, int lr, int lk) {
    Frag f;
    f.h0 = *(const half8*)(B + (i * 16 + lr) * LDH + lk * 8);
    f.h1 = *(const half8*)(B + (i * 16 + lr) * LDH + 32 + lk * 8);
    return f;
}

__device__ __forceinline__ void mfma_acc(const Frag& a, const Frag& b, f32x4& acc) {
    acc = __builtin_amdgcn_mfma_f32_16x16x32_f16(a.h0, b.h0, acc, 0, 0, 0);
    acc = __builtin_amdgcn_mfma_f32_16x16x32_f16(a.h1, b.h1, acc, 0, 0, 0);
}

struct NmfLds {
    _Float16 U_rm[64 * LDH];
    _Float16 U_cm[64 * LDH];
    _Float16 V_rm[64 * LDH];
    _Float16 V_cm[64 * LDH];
    _Float16 WZ[64 * LDH];  // W then Y each iter (both symmetric -> cm store == rm)
    float vsum[64];
};

__global__ __launch_bounds__(256, 3) void nmf_kernel(const float* __restrict__ Ag,
                                                     const float* __restrict__ U0,
                                                     const float* __restrict__ V0,
                                                     float* __restrict__ out,
                                                     float* __restrict__ ws) {
    __shared__ NmfLds S;
    const int b = blockIdx.x;
    const int tid = threadIdx.x;
    const int wave = tid >> 6;
    const int lane = tid & 63;
    const int lr = lane & 15;
    const int lk = lane >> 4;

    const float* Ab = Ag + (size_t)b * 4096;
    const float* Ub = U0 + (size_t)b * 4096;
    const float* Vb = V0 + (size_t)b * 4096;

    float Ureg[4][4], Vreg[4][4];  // [t][q] at (r = wave*16+lk*4+q, c = t*16+lr)

    // ---- init: stage A (rm -> WZ, cm -> U_rm temp), capture frags, then write U,V ----
#pragma unroll
    for (int t = 0; t < 4; ++t)
#pragma unroll
        for (int q = 0; q < 4; ++q) {
            const int r = wave * 16 + lk * 4 + q;
            const int c = t * 16 + lr;
            float a = Ab[r * 64 + c];
            S.WZ[r * LDH + c] = (_Float16)a;    // A row-major
            S.U_rm[c * LDH + r] = (_Float16)a;  // A col-major (temp)
        }
    __syncthreads();
    Frag af[4];  // A_cm fragments (persistent, registers)
#pragma unroll
    for (int i = 0; i < 4; ++i) af[i] = load_frag(S.U_rm, i, lr, lk);
    Frag arm = load_frag(S.WZ, wave, lr, lk);  // A_rm own strip (persistent)
    __syncthreads();  // frags captured; temp buffers may be overwritten

#pragma unroll
    for (int t = 0; t < 4; ++t)
#pragma unroll
        for (int q = 0; q < 4; ++q) {
            const int r = wave * 16 + lk * 4 + q;
            const int c = t * 16 + lr;
            float u = softplus_f(Ub[r * 64 + c]);
            Ureg[t][q] = u;
            S.U_rm[r * LDH + c] = (_Float16)u;
            S.U_cm[c * LDH + r] = (_Float16)u;
            float v = softplus_f(Vb[r * 64 + c]);
            Vreg[t][q] = v;
            S.V_rm[r * LDH + c] = (_Float16)v;
            S.V_cm[c * LDH + r] = (_Float16)v;
        }
    __syncthreads();

    const f32x4 zero4 = {0.f, 0.f, 0.f, 0.f};

    for (int it = 0; it < 10; ++it) {
        // ---- Phase A: T1 = U^T A ; W = U^T U (fragment-shared) ----
        Frag ucself = load_frag(S.U_cm, wave, lr, lk);
        Frag uf[4];
#pragma unroll
        for (int i = 0; i < 4; ++i) uf[i] = load_frag(S.U_cm, i, lr, lk);
        f32x4 T1[4] = {zero4, zero4, zero4, zero4};
        f32x4 W[4] = {zero4, zero4, zero4, zero4};
#pragma unroll
        for (int ct = 0; ct < 4; ++ct) {
            mfma_acc(ucself, af[ct], T1[ct]);
            mfma_acc(ucself, uf[ct], W[ct]);
        }
        // store W (symmetric): thread (r,c) -> WZ[c*LDH + r], 4 consecutive r -> b64
#pragma unroll
        for (int t = 0; t < 4; ++t) {
            half4 p = {(_Float16)W[t][0], (_Float16)W[t][1], (_Float16)W[t][2],
                       (_Float16)W[t][3]};
            *(half4*)(S.WZ + (t * 16 + lr) * LDH + wave * 16 + lk * 4) = p;
        }
        __syncthreads();  // b1: W ready

        // ---- Phase B: WV = W @ V ----
        Frag wf = load_frag(S.WZ, wave, lr, lk);
        Frag vcf[4];
#pragma unroll
        for (int i = 0; i < 4; ++i) vcf[i] = load_frag(S.V_cm, i, lr, lk);
        f32x4 WV[4] = {zero4, zero4, zero4, zero4};
#pragma unroll
        for (int ct = 0; ct < 4; ++ct) mfma_acc(wf, vcf[ct], WV[ct]);
        __syncthreads();  // b2: all reads of old V_cm complete

        // ---- Phase C: V *= T1 / (WV + eps) ----
#pragma unroll
        for (int t = 0; t < 4; ++t) {
            half4 p;
#pragma unroll
            for (int q = 0; q < 4; ++q) {
                float v = Vreg[t][q] * T1[t][q] * __builtin_amdgcn_rcpf(WV[t][q] + EPS);
                Vreg[t][q] = v;
                _Float16 h = (_Float16)v;
                p[q] = h;
                S.V_rm[(wave * 16 + lk * 4 + q) * LDH + t * 16 + lr] = h;
            }
            *(half4*)(S.V_cm + (t * 16 + lr) * LDH + wave * 16 + lk * 4) = p;
        }
        __syncthreads();  // b3: new V visible

        // ---- Phase D: T2 = A V^T ; Y = V V^T (fragment-shared) ----
        Frag vrself = load_frag(S.V_rm, wave, lr, lk);
        Frag vrf[4];
#pragma unroll
        for (int i = 0; i < 4; ++i) vrf[i] = load_frag(S.V_rm, i, lr, lk);
        f32x4 T2[4] = {zero4, zero4, zero4, zero4};
        f32x4 Y[4] = {zero4, zero4, zero4, zero4};
#pragma unroll
        for (int ct = 0; ct < 4; ++ct) {
            mfma_acc(arm, vrf[ct], T2[ct]);
            mfma_acc(vrself, vrf[ct], Y[ct]);
        }
#pragma unroll
        for (int t = 0; t < 4; ++t) {
            half4 p = {(_Float16)Y[t][0], (_Float16)Y[t][1], (_Float16)Y[t][2],
                       (_Float16)Y[t][3]};
            *(half4*)(S.WZ + (t * 16 + lr) * LDH + wave * 16 + lk * 4) = p;
        }
        __syncthreads();  // b4: Y ready

        // ---- Phase E: ZVT = U @ Y ; U *= T2 / (ZVT + eps) ----
        Frag urf = load_frag(S.U_rm, wave, lr, lk);
        Frag yf[4];
#pragma unroll
        for (int i = 0; i < 4; ++i) yf[i] = load_frag(S.WZ, i, lr, lk);
        f32x4 ZV[4] = {zero4, zero4, zero4, zero4};
#pragma unroll
        for (int ct = 0; ct < 4; ++ct) mfma_acc(urf, yf[ct], ZV[ct]);
#pragma unroll
        for (int t = 0; t < 4; ++t) {
            half4 p;
#pragma unroll
            for (int q = 0; q < 4; ++q) {
                float u = Ureg[t][q] * T2[t][q] * __builtin_amdgcn_rcpf(ZV[t][q] + EPS);
                Ureg[t][q] = u;
                _Float16 h = (_Float16)u;
                p[q] = h;
                S.U_rm[(wave * 16 + lk * 4 + q) * LDH + t * 16 + lr] = h;
            }
            *(half4*)(S.U_cm + (t * 16 + lr) * LDH + wave * 16 + lk * 4) = p;
        }
        __syncthreads();  // b5: new U visible for next iter
    }

    // ---- vsum / rs (structural attention row sums) ----
#pragma unroll
    for (int q = 0; q < 4; ++q) {
        float p = Vreg[0][q] + Vreg[1][q] + Vreg[2][q] + Vreg[3][q];
        p += __shfl_xor(p, 1);
        p += __shfl_xor(p, 2);
        p += __shfl_xor(p, 4);
        p += __shfl_xor(p, 8);
        if (lr == 0) S.vsum[wave * 16 + lk * 4 + q] = p;
    }
    __syncthreads();
#pragma unroll
    for (int q = 0; q < 4; ++q) {
        float p = 0.f;
#pragma unroll
        for (int t = 0; t < 4; ++t) p += Ureg[t][q] * S.vsum[t * 16 + lr];
        p += __shfl_xor(p, 1);
        p += __shfl_xor(p, 2);
        p += __shfl_xor(p, 4);
        p += __shfl_xor(p, 8);
        if (lr == 0) ws[(size_t)b * 64 + wave * 16 + lk * 4 + q] = p;
    }

    // ---- coalesced U,V output via LDS repack (fp16-rounded, << 2% threshold) ----
    {
        float* Uout = out + 8650752 + (size_t)b * 4096;
        float* Vout = out + 17039360 + (size_t)b * 4096;
        const int rr = tid >> 2, qt = tid & 3;
        const _Float16* Up = S.U_rm + rr * LDH + qt * 16;
        const _Float16* Vp = S.V_rm + rr * LDH + qt * 16;
        half8 u0 = *(const half8*)(Up), u1 = *(const half8*)(Up + 8);
        half8 v0 = *(const half8*)(Vp), v1 = *(const half8*)(Vp + 8);
        float4* Uo = (float4*)(Uout + rr * 64 + qt * 16);
        float4* Vo = (float4*)(Vout + rr * 64 + qt * 16);
        Uo[0] = {(float)u0[0], (float)u0[1], (float)u0[2], (float)u0[3]};
        Uo[1] = {(float)u0[4], (float)u0[5], (float)u0[6], (float)u0[7]};
        Uo[2] = {(float)u1[0], (float)u1[1], (float)u1[2], (float)u1[3]};
        Uo[3] = {(float)u1[4], (float)u1[5], (float)u1[6], (float)u1[7]};
        Vo[0] = {(float)v0[0], (float)v0[1], (float)v0[2], (float)v0[3]};
        Vo[1] = {(float)v0[4], (float)v0[5], (float)v0[6], (float)v0[7]};
        Vo[2] = {(float)v1[0], (float)v1[1], (float)v1[2], (float)v1[3]};
        Vo[3] = {(float)v1[4], (float)v1[5], (float)v1[6], (float)v1[7]};
    }
}

__global__ __launch_bounds__(256) void xp_kernel(const float* __restrict__ Xg,
                                                 const float* __restrict__ xn,
                                                 float* __restrict__ out,
                                                 float* __restrict__ ws) {
    __shared__ float X[128 * 65];
    __shared__ float xnew[128];
    __shared__ float red[256];
    __shared__ float tbuf[64];
    __shared__ float xp[128];
    const int b = blockIdx.x, tid = threadIdx.x;
    const float* Xb = Xg + (size_t)b * 8192;

    for (int idx = tid; idx < 2048; idx += 256) {
        float4 v = ((const float4*)Xb)[idx];
        int d = idx >> 4, n = (idx * 4) & 63;
        X[d * 65 + n + 0] = v.x;
        X[d * 65 + n + 1] = v.y;
        X[d * 65 + n + 2] = v.z;
        X[d * 65 + n + 3] = v.w;
    }
    if (tid < 32) {
        float4 v = ((const float4*)(xn + (size_t)b * 128))[tid];
        xnew[tid * 4 + 0] = v.x;
        xnew[tid * 4 + 1] = v.y;
        xnew[tid * 4 + 2] = v.z;
        xnew[tid * 4 + 3] = v.w;
    }
    __syncthreads();
    {
        const int n = tid & 63, g = tid >> 6;
        float p = 0.f;
        for (int d = g * 32; d < g * 32 + 32; ++d) p += xnew[d] * X[d * 65 + n];
        red[g * 64 + n] = p;
    }
    __syncthreads();
    if (tid < 64) tbuf[tid] = red[tid] + red[64 + tid] + red[128 + tid] + red[192 + tid];
    __syncthreads();
    {
        const int d = tid & 127, h = tid >> 7;
        float p = 0.f;
        for (int n = h * 32; n < h * 32 + 32; ++n) p += X[d * 65 + n] * tbuf[n];
        red[h * 128 + d] = p;
    }
    __syncthreads();
    if (tid < 128) {
        float v = red[tid] + red[128 + tid];
        xp[tid] = v;
        out[8388608 + (size_t)b * 128 + tid] = v;
    }
    __syncthreads();
    {
        const int n = tid & 63, g = tid >> 6;
        float p = 0.f;
        for (int d = g * 32; d < g * 32 + 32; ++d) p += xp[d] * X[d * 65 + n];
        red[g * 64 + n] = p;
    }
    __syncthreads();
    if (tid < 64)
        ws[131072 + (size_t)b * 64 + tid] =
            red[tid] + red[64 + tid] + red[128 + tid] + red[192 + tid];
}

__global__ __launch_bounds__(256) void fuse_kernel(const float* __restrict__ ws,
                                                   float* __restrict__ out) {
    __shared__ float g[64];
    __shared__ float rs[64];
    __shared__ float gmax_s;
    const int b = blockIdx.x, tid = threadIdx.x;
    if (tid < 64) {
        float s = ws[131072 + (size_t)b * 64 + tid];
        g[tid] = s * s * 0.088388347648318447f;  // 1/sqrt(128)
        rs[tid] = ws[(size_t)b * 64 + tid];
    }
    __syncthreads();
    if (tid < 64) {
        float m = g[tid];
#pragma unroll
        for (int o = 1; o < 64; o <<= 1) m = fmaxf(m, __shfl_xor(m, o));
        if (tid == 0) gmax_s = m;
    }
    __syncthreads();
    const float gmax = gmax_s;
    const int i = tid >> 2, part = tid & 3;
    const float r = rs[i];
    float e[16];
    float sum = 0.f;
#pragma unroll
    for (int j = 0; j < 16; ++j) {
        e[j] = expf(r * (g[part * 16 + j] - gmax));
        sum += e[j];
    }
    sum += __shfl_xor(sum, 1);
    sum += __shfl_xor(sum, 2);
    const float inv = 1.f / sum;
    float* o = out + (size_t)b * 4096 + i * 64 + part * 16;
#pragma unroll
    for (int j = 0; j < 16; j += 4) {
        float4 v = {e[j] * inv, e[j + 1] * inv, e[j + 2] * inv, e[j + 3] * inv};
        ((float4*)o)[j >> 2] = v;
    }
}

extern "C" void kernel_launch(void* const* d_in, const int* in_sizes, int n_in,
                              void* d_out, int out_size, void* d_ws, size_t ws_size,
                              hipStream_t stream) {
    (void)in_sizes; (void)n_in; (void)out_size; (void)ws_size;
    const float* Ag = (const float*)d_in[0];
    const float* Xg = (const float*)d_in[1];
    const float* xn = (const float*)d_in[2];
    const float* U0 = (const float*)d_in[3];
    const float* V0 = (const float*)d_in[4];
    float* out = (float*)d_out;
    float* ws = (float*)d_ws;

    hipLaunchKernelGGL(nmf_kernel, dim3(2048), dim3(256), 0, stream, Ag, U0, V0, out, ws);
    hipLaunchKernelGGL(xp_kernel, dim3(2048), dim3(256), 0, stream, Xg, xn, out, ws);
    hipLaunchKernelGGL(fuse_kernel, dim3(2048), dim3(256), 0, stream, ws, out);
}

// Round 4
// 159.344 us; speedup vs baseline: 1.5180x; 1.0524x over previous
//
#include <hip/hip_runtime.h>
#include <hip/hip_bf16.h>

#define EPS 1e-8f

typedef _Float16 half8 __attribute__((ext_vector_type(8)));
typedef _Float16 half4 __attribute__((ext_vector_type(4)));
typedef float f32x4 __attribute__((ext_vector_type(4)));

__device__ __forceinline__ float softplus_f(float x) {
    return fmaxf(x, 0.f) + log1pf(expf(-fabsf(x)));
}

// Swizzled half-index for a 64x64 fp16 LDS tile, zero padding.
// 8-half (16B) groups are XOR-permuted by row: bank profile equals the padded
// layout (minimal 8 lanes per 4-bank group on b128 strip loads) at 8192 B/buffer.
__device__ __forceinline__ int swzh(int r, int c) {
    return r * 64 + ((((c >> 3) ^ (r & 7)) << 3) | (c & 7));
}

struct Frag {  // 16-row strip of a 64x64 fp16 matrix: rows i*16+lr, k = 0..63
    half8 h0, h1;
};

__device__ __forceinline__ Frag load_frag(const _Float16* B, int i, int lr, int lk) {
    const int row = i * 16 + lr;
    const int x = lr & 7;
    Frag f;
    f.h0 = *(const half8*)(B + row * 64 + ((lk ^ x) << 3));
    f.h1 = *(const half8*)(B + row * 64 + (((lk + 4) ^ x) << 3));
    return f;
}

__device__ __forceinline__ void mfma_acc(const Frag& a, const Frag& b, f32x4& acc) {
    acc = __builtin_amdgcn_mfma_f32_16x16x32_f16(a.h0, b.h0, acc, 0, 0, 0);
    acc = __builtin_amdgcn_mfma_f32_16x16x32_f16(a.h1, b.h1, acc, 0, 0, 0);
}

struct NmfLds {
    _Float16 U_rm[4096];  // U row-major
    _Float16 U_cm[4096];  // U^T row-major
    _Float16 V_rm[4096];  // V row-major
    _Float16 V_cm[4096];  // V^T row-major (wave-private strips)
    union {
        _Float16 WZ[4096];  // W then Y (symmetric) per iter
        float vp[4][64];    // post-loop: per-wave vsum partials
    } u;
};  // 40960 B -> 4 blocks/CU exactly

__global__ __launch_bounds__(256, 4) void nmf_kernel(const float* __restrict__ Ag,
                                                     const float* __restrict__ U0,
                                                     const float* __restrict__ V0,
                                                     float* __restrict__ out,
                                                     float* __restrict__ ws) {
    __shared__ NmfLds S;
    const int b = blockIdx.x;
    const int tid = threadIdx.x;
    const int wave = tid >> 6;
    const int lane = tid & 63;
    const int lr = lane & 15;
    const int lk = lane >> 4;

    const float* Ab = Ag + (size_t)b * 4096;
    const float* Ub = U0 + (size_t)b * 4096;
    const float* Vb = V0 + (size_t)b * 4096;

    float Ureg[4][4];   // U[r'][c'],  r' = wave*16+lk*4+q, c' = t*16+lr
    float VregT[4][4];  // V^T[r'][c'] = V[c'][r']

    // ---- stage A into U_rm (A rm) / U_cm (A^T rm) temporarily, capture frags ----
#pragma unroll
    for (int t = 0; t < 4; ++t)
#pragma unroll
        for (int q = 0; q < 4; ++q) {
            const int r = wave * 16 + lk * 4 + q;
            const int c = t * 16 + lr;
            float a = Ab[r * 64 + c];
            S.U_rm[swzh(r, c)] = (_Float16)a;
            S.U_cm[swzh(c, r)] = (_Float16)a;
        }
    __syncthreads();
    const Frag arm = load_frag(S.U_rm, wave, lr, lk);  // A rm self-strip
    const Frag acm = load_frag(S.U_cm, wave, lr, lk);  // A^T rm self-strip
    __syncthreads();  // frags captured; temp regions reusable

    // ---- init U (untransposed regs), V (transposed regs) ----
#pragma unroll
    for (int t = 0; t < 4; ++t)
#pragma unroll
        for (int q = 0; q < 4; ++q) {
            const int r = wave * 16 + lk * 4 + q;
            const int c = t * 16 + lr;
            float uv = softplus_f(Ub[r * 64 + c]);
            Ureg[t][q] = uv;
            S.U_rm[swzh(r, c)] = (_Float16)uv;
            S.U_cm[swzh(c, r)] = (_Float16)uv;
            float vv = softplus_f(Vb[c * 64 + r]);  // V[c][r] = V^T[r][c]
            VregT[t][q] = vv;
            S.V_cm[swzh(r, c)] = (_Float16)vv;  // V^T rm
            S.V_rm[swzh(c, r)] = (_Float16)vv;  // V rm
        }
    __syncthreads();

    const f32x4 zero4 = {0.f, 0.f, 0.f, 0.f};

    for (int it = 0; it < 10; ++it) {
        // ---- S1: T1^T = A^T @ U ; W = U^T @ U  (B-strips shared) ----
        Frag ucself = load_frag(S.U_cm, wave, lr, lk);
        f32x4 T1T[4] = {zero4, zero4, zero4, zero4};
        f32x4 W[4] = {zero4, zero4, zero4, zero4};
#pragma unroll
        for (int ct = 0; ct < 4; ++ct) {
            Frag uct = load_frag(S.U_cm, ct, lr, lk);
            mfma_acc(acm, uct, T1T[ct]);
            mfma_acc(ucself, uct, W[ct]);
        }
        // store W (symmetric -> packed transposed store gives W rm)
#pragma unroll
        for (int t = 0; t < 4; ++t) {
            half4 p = {(_Float16)W[t][0], (_Float16)W[t][1], (_Float16)W[t][2],
                       (_Float16)W[t][3]};
            *(half4*)(&S.u.WZ[swzh(t * 16 + lr, wave * 16 + lk * 4)]) = p;
        }
        __syncthreads();  // b1: W ready

        // ---- S2: WV^T = V^T @ W  (V_cm self-strip is wave-private) ----
        Frag vtself = load_frag(S.V_cm, wave, lr, lk);
        f32x4 WVT[4] = {zero4, zero4, zero4, zero4};
#pragma unroll
        for (int ct = 0; ct < 4; ++ct) {
            Frag wct = load_frag(S.u.WZ, ct, lr, lk);
            mfma_acc(vtself, wct, WVT[ct]);
        }

        // ---- S3: V^T *= T1^T / (WV^T + eps) ----
#pragma unroll
        for (int t = 0; t < 4; ++t) {
            half4 p;
#pragma unroll
            for (int q = 0; q < 4; ++q) {
                float v =
                    VregT[t][q] * T1T[t][q] * __builtin_amdgcn_rcpf(WVT[t][q] + EPS);
                VregT[t][q] = v;
                _Float16 h = (_Float16)v;
                p[q] = h;
                S.V_cm[swzh(wave * 16 + lk * 4 + q, t * 16 + lr)] = h;  // private strip
            }
            *(half4*)(&S.V_rm[swzh(t * 16 + lr, wave * 16 + lk * 4)]) = p;  // V rm
        }
        __syncthreads();  // b3: new V visible

        // ---- S4: T2 = A @ V'^T ; Y = V' V'^T  (B-strips shared) ----
        Frag vrself = load_frag(S.V_rm, wave, lr, lk);
        f32x4 T2[4] = {zero4, zero4, zero4, zero4};
        f32x4 Y[4] = {zero4, zero4, zero4, zero4};
#pragma unroll
        for (int ct = 0; ct < 4; ++ct) {
            Frag vct = load_frag(S.V_rm, ct, lr, lk);
            mfma_acc(arm, vct, T2[ct]);
            mfma_acc(vrself, vct, Y[ct]);
        }
#pragma unroll
        for (int t = 0; t < 4; ++t) {
            half4 p = {(_Float16)Y[t][0], (_Float16)Y[t][1], (_Float16)Y[t][2],
                       (_Float16)Y[t][3]};
            *(half4*)(&S.u.WZ[swzh(t * 16 + lr, wave * 16 + lk * 4)]) = p;
        }
        __syncthreads();  // b4: Y ready

        // ---- S5: ZV = U @ Y  (U_rm self-strip is wave-private) ----
        Frag urself = load_frag(S.U_rm, wave, lr, lk);
        f32x4 ZV[4] = {zero4, zero4, zero4, zero4};
#pragma unroll
        for (int ct = 0; ct < 4; ++ct) {
            Frag yct = load_frag(S.u.WZ, ct, lr, lk);
            mfma_acc(urself, yct, ZV[ct]);
        }

        // ---- S6: U *= T2 / (ZV + eps) ----
#pragma unroll
        for (int t = 0; t < 4; ++t) {
            half4 p;
#pragma unroll
            for (int q = 0; q < 4; ++q) {
                float u = Ureg[t][q] * T2[t][q] * __builtin_amdgcn_rcpf(ZV[t][q] + EPS);
                Ureg[t][q] = u;
                _Float16 h = (_Float16)u;
                p[q] = h;
                S.U_rm[swzh(wave * 16 + lk * 4 + q, t * 16 + lr)] = h;  // private strip
            }
            *(half4*)(&S.U_cm[swzh(t * 16 + lr, wave * 16 + lk * 4)]) = p;  // U^T rm
        }
        __syncthreads();  // b5: new U visible for next iter
    }

    // ---- vsum via V^T column-sums, then rs = U @ vsum ----
    {
        float part[4];
#pragma unroll
        for (int t = 0; t < 4; ++t) {
            float s = VregT[t][0] + VregT[t][1] + VregT[t][2] + VregT[t][3];
            s += __shfl_xor(s, 16);
            s += __shfl_xor(s, 32);
            part[t] = s;
        }
        if (lk == 0) {
#pragma unroll
            for (int t = 0; t < 4; ++t) S.u.vp[wave][t * 16 + lr] = part[t];
        }
    }
    __syncthreads();
#pragma unroll
    for (int q = 0; q < 4; ++q) {
        float p = 0.f;
#pragma unroll
        for (int t = 0; t < 4; ++t) {
            float vs = S.u.vp[0][t * 16 + lr] + S.u.vp[1][t * 16 + lr] +
                       S.u.vp[2][t * 16 + lr] + S.u.vp[3][t * 16 + lr];
            p += Ureg[t][q] * vs;
        }
        p += __shfl_xor(p, 1);
        p += __shfl_xor(p, 2);
        p += __shfl_xor(p, 4);
        p += __shfl_xor(p, 8);
        if (lr == 0) ws[(size_t)b * 64 + wave * 16 + lk * 4 + q] = p;
    }

    // ---- coalesced U,V output via LDS repack ----
    {
        float* Uout = out + 8650752 + (size_t)b * 4096;
        float* Vout = out + 17039360 + (size_t)b * 4096;
        const int rr = tid >> 2, qt = tid & 3;
        const _Float16* Up = S.U_rm + swzh(rr, qt * 16);
        const _Float16* Vp = S.V_rm + swzh(rr, qt * 16);
        half8 u0 = *(const half8*)(Up);
        half8 u1 = *(const half8*)(S.U_rm + swzh(rr, qt * 16 + 8));
        half8 v0 = *(const half8*)(Vp);
        half8 v1 = *(const half8*)(S.V_rm + swzh(rr, qt * 16 + 8));
        float4* Uo = (float4*)(Uout + rr * 64 + qt * 16);
        float4* Vo = (float4*)(Vout + rr * 64 + qt * 16);
        Uo[0] = {(float)u0[0], (float)u0[1], (float)u0[2], (float)u0[3]};
        Uo[1] = {(float)u0[4], (float)u0[5], (float)u0[6], (float)u0[7]};
        Uo[2] = {(float)u1[0], (float)u1[1], (float)u1[2], (float)u1[3]};
        Uo[3] = {(float)u1[4], (float)u1[5], (float)u1[6], (float)u1[7]};
        Vo[0] = {(float)v0[0], (float)v0[1], (float)v0[2], (float)v0[3]};
        Vo[1] = {(float)v0[4], (float)v0[5], (float)v0[6], (float)v0[7]};
        Vo[2] = {(float)v1[0], (float)v1[1], (float)v1[2], (float)v1[3]};
        Vo[3] = {(float)v1[4], (float)v1[5], (float)v1[6], (float)v1[7]};
    }
}

__global__ __launch_bounds__(256) void xp_kernel(const float* __restrict__ Xg,
                                                 const float* __restrict__ xn,
                                                 float* __restrict__ out,
                                                 float* __restrict__ ws) {
    __shared__ float X[128 * 65];
    __shared__ float xnew[128];
    __shared__ float red[256];
    __shared__ float tbuf[64];
    __shared__ float xp[128];
    const int b = blockIdx.x, tid = threadIdx.x;
    const float* Xb = Xg + (size_t)b * 8192;

    for (int idx = tid; idx < 2048; idx += 256) {
        float4 v = ((const float4*)Xb)[idx];
        int d = idx >> 4, n = (idx * 4) & 63;
        X[d * 65 + n + 0] = v.x;
        X[d * 65 + n + 1] = v.y;
        X[d * 65 + n + 2] = v.z;
        X[d * 65 + n + 3] = v.w;
    }
    if (tid < 32) {
        float4 v = ((const float4*)(xn + (size_t)b * 128))[tid];
        xnew[tid * 4 + 0] = v.x;
        xnew[tid * 4 + 1] = v.y;
        xnew[tid * 4 + 2] = v.z;
        xnew[tid * 4 + 3] = v.w;
    }
    __syncthreads();
    {
        const int n = tid & 63, g = tid >> 6;
        float p = 0.f;
        for (int d = g * 32; d < g * 32 + 32; ++d) p += xnew[d] * X[d * 65 + n];
        red[g * 64 + n] = p;
    }
    __syncthreads();
    if (tid < 64) tbuf[tid] = red[tid] + red[64 + tid] + red[128 + tid] + red[192 + tid];
    __syncthreads();
    {
        const int d = tid & 127, h = tid >> 7;
        float p = 0.f;
        for (int n = h * 32; n < h * 32 + 32; ++n) p += X[d * 65 + n] * tbuf[n];
        red[h * 128 + d] = p;
    }
    __syncthreads();
    if (tid < 128) {
        float v = red[tid] + red[128 + tid];
        xp[tid] = v;
        out[8388608 + (size_t)b * 128 + tid] = v;
    }
    __syncthreads();
    {
        const int n = tid & 63, g = tid >> 6;
        float p = 0.f;
        for (int d = g * 32; d < g * 32 + 32; ++d) p += xp[d] * X[d * 65 + n];
        red[g * 64 + n] = p;
    }
    __syncthreads();
    if (tid < 64)
        ws[131072 + (size_t)b * 64 + tid] =
            red[tid] + red[64 + tid] + red[128 + tid] + red[192 + tid];
}

__global__ __launch_bounds__(256) void fuse_kernel(const float* __restrict__ ws,
                                                   float* __restrict__ out) {
    __shared__ float g[64];
    __shared__ float rs[64];
    __shared__ float gmax_s;
    const int b = blockIdx.x, tid = threadIdx.x;
    if (tid < 64) {
        float s = ws[131072 + (size_t)b * 64 + tid];
        g[tid] = s * s * 0.088388347648318447f;  // 1/sqrt(128)
        rs[tid] = ws[(size_t)b * 64 + tid];
    }
    __syncthreads();
    if (tid < 64) {
        float m = g[tid];
#pragma unroll
        for (int o = 1; o < 64; o <<= 1) m = fmaxf(m, __shfl_xor(m, o));
        if (tid == 0) gmax_s = m;
    }
    __syncthreads();
    const float gmax = gmax_s;
    const int i = tid >> 2, part = tid & 3;
    const float r = rs[i];
    float e[16];
    float sum = 0.f;
#pragma unroll
    for (int j = 0; j < 16; ++j) {
        e[j] = expf(r * (g[part * 16 + j] - gmax));
        sum += e[j];
    }
    sum += __shfl_xor(sum, 1);
    sum += __shfl_xor(sum, 2);
    const float inv = 1.f / sum;
    float* o = out + (size_t)b * 4096 + i * 64 + part * 16;
#pragma unroll
    for (int j = 0; j < 16; j += 4) {
        float4 v = {e[j] * inv, e[j + 1] * inv, e[j + 2] * inv, e[j + 3] * inv};
        ((float4*)o)[j >> 2] = v;
    }
}

extern "C" void kernel_launch(void* const* d_in, const int* in_sizes, int n_in,
                              void* d_out, int out_size, void* d_ws, size_t ws_size,
                              hipStream_t stream) {
    (void)in_sizes; (void)n_in; (void)out_size; (void)ws_size;
    const float* Ag = (const float*)d_in[0];
    const float* Xg = (const float*)d_in[1];
    const float* xn = (const float*)d_in[2];
    const float* U0 = (const float*)d_in[3];
    const float* V0 = (const float*)d_in[4];
    float* out = (float*)d_out;
    float* ws = (float*)d_ws;

    hipLaunchKernelGGL(nmf_kernel, dim3(2048), dim3(256), 0, stream, Ag, U0, V0, out, ws);
    hipLaunchKernelGGL(xp_kernel, dim3(2048), dim3(256), 0, stream, Xg, xn, out, ws);
    hipLaunchKernelGGL(fuse_kernel, dim3(2048), dim3(256), 0, stream, ws, out);
}

// Round 5
// 155.278 us; speedup vs baseline: 1.5577x; 1.0262x over previous
//
#include <hip/hip_runtime.h>
#include <hip/hip_bf16.h>

#define EPS 1e-8f

typedef _Float16 half8 __attribute__((ext_vector_type(8)));
typedef _Float16 half4 __attribute__((ext_vector_type(4)));
typedef float f32x4 __attribute__((ext_vector_type(4)));

__device__ __forceinline__ float softplus_f(float x) {
    return fmaxf(x, 0.f) + log1pf(expf(-fabsf(x)));
}

// Swizzled half-index for a 64x64 fp16 LDS tile (8192 B, no padding).
// 8-half (16B) groups XOR-permuted by row&7: b128 strip loads are 2-way max.
__device__ __forceinline__ int swzh(int r, int c) {
    return r * 64 + ((((c >> 3) ^ (r & 7)) << 3) | (c & 7));
}

struct Frag {  // 16-row strip: rows i*16+lr, k = 0..63
    half8 h0, h1;
};

// Strip load from two precomputed swizzled base pointers (row lr, groups lk / lk+4).
// Strip CT offset = CT*1024 halves (row+16 preserves r&7 -> swizzle invariant).
template <int CT>
__device__ __forceinline__ Frag load_strip(const _Float16* p0, const _Float16* p1) {
    Frag f;
    f.h0 = *(const half8*)(p0 + CT * 1024);
    f.h1 = *(const half8*)(p1 + CT * 1024);
    return f;
}

__device__ __forceinline__ void mfma_acc(const Frag& a, const Frag& b, f32x4& acc) {
    acc = __builtin_amdgcn_mfma_f32_16x16x32_f16(a.h0, b.h0, acc, 0, 0, 0);
    acc = __builtin_amdgcn_mfma_f32_16x16x32_f16(a.h1, b.h1, acc, 0, 0, 0);
}

struct NmfLds {
    _Float16 V_cm[4096];  // V^T row-major (wave-private strips)   [base 0]
    _Float16 U_rm[4096];  // U row-major (self-strip scalar stores: +4096 halves)
    _Float16 U_cm[4096];  // U^T row-major
    _Float16 V_rm[4096];  // V row-major
    union {
        _Float16 WZ[4096];  // W then Y (symmetric) per iter
        float vp[4][64];    // post-loop vsum partials
    } u;
};  // 40960 B -> 4 blocks/CU

__global__ __launch_bounds__(256, 4) void nmf_kernel(const float* __restrict__ Ag,
                                                     const float* __restrict__ U0,
                                                     const float* __restrict__ V0,
                                                     float* __restrict__ out,
                                                     float* __restrict__ ws) {
    __shared__ NmfLds S;
    const int b = blockIdx.x;
    const int tid = threadIdx.x;
    const int wave = tid >> 6;
    const int lane = tid & 63;
    const int lr = lane & 15;
    const int lk = lane >> 4;
    const int x = lr & 7;

    const float* Ab = Ag + (size_t)b * 4096;
    const float* Ub = U0 + (size_t)b * 4096;
    const float* Vb = V0 + (size_t)b * 4096;

    float Ureg[4][4];   // U[r'][c'],  r' = wave*16+lk*4+q, c' = t*16+lr
    float VregT[4][4];  // V^T[r'][c']

    // ---- precomputed swizzled LDS addresses (all loop-invariant) ----
    const int sg0 = (lk ^ x) << 3;        // self/strip group offset, h0
    const int sg1 = ((lk + 4) ^ x) << 3;  // h1
    // ct-strip read bases (row = lr)
    const _Float16* rUcm0 = S.U_cm + lr * 64 + sg0;
    const _Float16* rUcm1 = S.U_cm + lr * 64 + sg1;
    const _Float16* rVrm0 = S.V_rm + lr * 64 + sg0;
    const _Float16* rVrm1 = S.V_rm + lr * 64 + sg1;
    const _Float16* rWZ0 = S.u.WZ + lr * 64 + sg0;
    const _Float16* rWZ1 = S.u.WZ + lr * 64 + sg1;
    // self-strip read bases (row = wave*16+lr)
    const int srow = (wave * 16 + lr) * 64;
    const _Float16* sUrm0 = S.U_rm + srow + sg0;
    const _Float16* sUrm1 = S.U_rm + srow + sg1;
    const _Float16* sUcm0 = S.U_cm + srow + sg0;
    const _Float16* sUcm1 = S.U_cm + srow + sg1;
    const _Float16* sVcm0 = S.V_cm + srow + sg0;
    const _Float16* sVcm1 = S.V_cm + srow + sg1;
    const _Float16* sVrm0 = S.V_rm + srow + sg0;
    const _Float16* sVrm1 = S.V_rm + srow + sg1;
    // transposed half4 store bases (row = t*16+lr -> +t*1024; col = wave*16+lk*4)
    const int cg = ((wave * 2 + (lk >> 1)) ^ x) << 3;
    const int bg = (lk & 1) << 2;
    _Float16* wtrV = S.V_rm + lr * 64 + cg + bg;
    _Float16* wtrU = S.U_cm + lr * 64 + cg + bg;
    _Float16* wtrW = S.u.WZ + lr * 64 + cg + bg;
    // scalar self-store half-offsets: addr(q,t) = oq[q] ^ (t<<4)  (V_cm; U_rm = +4096)
    const int g0 = lr >> 3;
    int oq[4];
#pragma unroll
    for (int q = 0; q < 4; ++q)
        oq[q] = (wave * 16 + lk * 4 + q) * 64 + ((g0 ^ ((lk * 4 + q) & 7)) << 3) + x;

    // ---- stage A into U_rm (A rm) / U_cm (A^T rm) temporarily, capture frags ----
#pragma unroll
    for (int t = 0; t < 4; ++t)
#pragma unroll
        for (int q = 0; q < 4; ++q) {
            const int r = wave * 16 + lk * 4 + q;
            const int c = t * 16 + lr;
            float a = Ab[r * 64 + c];
            S.U_rm[swzh(r, c)] = (_Float16)a;
            S.U_cm[swzh(c, r)] = (_Float16)a;
        }
    __syncthreads();
    const Frag arm = load_strip<0>(sUrm0, sUrm1);  // A rm self-strip
    const Frag acm = load_strip<0>(sUcm0, sUcm1);  // A^T rm self-strip
    __syncthreads();  // frags captured; temp regions reusable

    // ---- init U (untransposed regs), V (transposed regs) ----
#pragma unroll
    for (int t = 0; t < 4; ++t)
#pragma unroll
        for (int q = 0; q < 4; ++q) {
            const int r = wave * 16 + lk * 4 + q;
            const int c = t * 16 + lr;
            float uv = softplus_f(Ub[r * 64 + c]);
            Ureg[t][q] = uv;
            S.U_rm[swzh(r, c)] = (_Float16)uv;
            S.U_cm[swzh(c, r)] = (_Float16)uv;
            float vv = softplus_f(Vb[c * 64 + r]);  // V^T[r][c]
            VregT[t][q] = vv;
            S.V_cm[swzh(r, c)] = (_Float16)vv;
            S.V_rm[swzh(c, r)] = (_Float16)vv;
        }
    __syncthreads();

    const f32x4 zero4 = {0.f, 0.f, 0.f, 0.f};

    for (int it = 0; it < 10; ++it) {
        // ---- S1: T1^T = A^T @ U ; W = U^T @ U ----
        Frag ucself = load_strip<0>(sUcm0, sUcm1);
        f32x4 T1T[4] = {zero4, zero4, zero4, zero4};
        f32x4 W[4] = {zero4, zero4, zero4, zero4};
#define S1STEP(CT)                                \
    {                                             \
        Frag uct = load_strip<CT>(rUcm0, rUcm1);  \
        mfma_acc(acm, uct, T1T[CT]);              \
        mfma_acc(ucself, uct, W[CT]);             \
    }
        S1STEP(0) S1STEP(1) S1STEP(2) S1STEP(3)
#pragma unroll
        for (int t = 0; t < 4; ++t) {
            half4 p = {(_Float16)W[t][0], (_Float16)W[t][1], (_Float16)W[t][2],
                       (_Float16)W[t][3]};
            *(half4*)(wtrW + t * 1024) = p;
        }
        __syncthreads();  // b1: W ready

        // ---- S2: WV^T = V^T @ W ----
        Frag vtself = load_strip<0>(sVcm0, sVcm1);
        f32x4 WVT[4] = {zero4, zero4, zero4, zero4};
#define S2STEP(CT)                               \
    {                                            \
        Frag wct = load_strip<CT>(rWZ0, rWZ1);   \
        mfma_acc(vtself, wct, WVT[CT]);          \
    }
        S2STEP(0) S2STEP(1) S2STEP(2) S2STEP(3)

        // ---- S3: V^T *= T1^T / (WV^T + eps) ----
#pragma unroll
        for (int t = 0; t < 4; ++t) {
            half4 p;
#pragma unroll
            for (int q = 0; q < 4; ++q) {
                float v =
                    VregT[t][q] * T1T[t][q] * __builtin_amdgcn_rcpf(WVT[t][q] + EPS);
                VregT[t][q] = v;
                _Float16 h = (_Float16)v;
                p[q] = h;
                S.V_cm[oq[q] ^ (t << 4)] = h;  // wave-private self strip
            }
            *(half4*)(wtrV + t * 1024) = p;
        }
        __syncthreads();  // b3: new V visible

        // ---- S4: T2 = A @ V'^T ; Y = V' V'^T ----
        Frag vrself = load_strip<0>(sVrm0, sVrm1);
        f32x4 T2[4] = {zero4, zero4, zero4, zero4};
        f32x4 Y[4] = {zero4, zero4, zero4, zero4};
#define S4STEP(CT)                                \
    {                                             \
        Frag vct = load_strip<CT>(rVrm0, rVrm1);  \
        mfma_acc(arm, vct, T2[CT]);               \
        mfma_acc(vrself, vct, Y[CT]);             \
    }
        S4STEP(0) S4STEP(1) S4STEP(2) S4STEP(3)
#pragma unroll
        for (int t = 0; t < 4; ++t) {
            half4 p = {(_Float16)Y[t][0], (_Float16)Y[t][1], (_Float16)Y[t][2],
                       (_Float16)Y[t][3]};
            *(half4*)(wtrW + t * 1024) = p;
        }
        __syncthreads();  // b4: Y ready

        // ---- S5: ZV = U @ Y ----
        Frag urself = load_strip<0>(sUrm0, sUrm1);
        f32x4 ZV[4] = {zero4, zero4, zero4, zero4};
#define S5STEP(CT)                              \
    {                                           \
        Frag yct = load_strip<CT>(rWZ0, rWZ1);  \
        mfma_acc(urself, yct, ZV[CT]);          \
    }
        S5STEP(0) S5STEP(1) S5STEP(2) S5STEP(3)

        // ---- S6: U *= T2 / (ZV + eps) ----
#pragma unroll
        for (int t = 0; t < 4; ++t) {
            half4 p;
#pragma unroll
            for (int q = 0; q < 4; ++q) {
                float u = Ureg[t][q] * T2[t][q] * __builtin_amdgcn_rcpf(ZV[t][q] + EPS);
                Ureg[t][q] = u;
                _Float16 h = (_Float16)u;
                p[q] = h;
                S.U_rm[oq[q] ^ (t << 4)] = h;  // wave-private self strip (+4096 base)
            }
            *(half4*)(wtrU + t * 1024) = p;
        }
        __syncthreads();  // b5: new U visible
    }

    // ---- vsum via V^T column-sums, then rs = U @ vsum ----
    {
        float part[4];
#pragma unroll
        for (int t = 0; t < 4; ++t) {
            float s = VregT[t][0] + VregT[t][1] + VregT[t][2] + VregT[t][3];
            s += __shfl_xor(s, 16);
            s += __shfl_xor(s, 32);
            part[t] = s;
        }
        if (lk == 0) {
#pragma unroll
            for (int t = 0; t < 4; ++t) S.u.vp[wave][t * 16 + lr] = part[t];
        }
    }
    __syncthreads();
#pragma unroll
    for (int q = 0; q < 4; ++q) {
        float p = 0.f;
#pragma unroll
        for (int t = 0; t < 4; ++t) {
            float vs = S.u.vp[0][t * 16 + lr] + S.u.vp[1][t * 16 + lr] +
                       S.u.vp[2][t * 16 + lr] + S.u.vp[3][t * 16 + lr];
            p += Ureg[t][q] * vs;
        }
        p += __shfl_xor(p, 1);
        p += __shfl_xor(p, 2);
        p += __shfl_xor(p, 4);
        p += __shfl_xor(p, 8);
        if (lr == 0) ws[(size_t)b * 64 + wave * 16 + lk * 4 + q] = p;
    }

    // ---- coalesced U,V output via LDS repack ----
    {
        float* Uout = out + 8650752 + (size_t)b * 4096;
        float* Vout = out + 17039360 + (size_t)b * 4096;
        const int rr = tid >> 2, qt = tid & 3;
        half8 u0 = *(const half8*)(S.U_rm + swzh(rr, qt * 16));
        half8 u1 = *(const half8*)(S.U_rm + swzh(rr, qt * 16 + 8));
        half8 v0 = *(const half8*)(S.V_rm + swzh(rr, qt * 16));
        half8 v1 = *(const half8*)(S.V_rm + swzh(rr, qt * 16 + 8));
        float4* Uo = (float4*)(Uout + rr * 64 + qt * 16);
        float4* Vo = (float4*)(Vout + rr * 64 + qt * 16);
        Uo[0] = {(float)u0[0], (float)u0[1], (float)u0[2], (float)u0[3]};
        Uo[1] = {(float)u0[4], (float)u0[5], (float)u0[6], (float)u0[7]};
        Uo[2] = {(float)u1[0], (float)u1[1], (float)u1[2], (float)u1[3]};
        Uo[3] = {(float)u1[4], (float)u1[5], (float)u1[6], (float)u1[7]};
        Vo[0] = {(float)v0[0], (float)v0[1], (float)v0[2], (float)v0[3]};
        Vo[1] = {(float)v0[4], (float)v0[5], (float)v0[6], (float)v0[7]};
        Vo[2] = {(float)v1[0], (float)v1[1], (float)v1[2], (float)v1[3]};
        Vo[3] = {(float)v1[4], (float)v1[5], (float)v1[6], (float)v1[7]};
    }
}

__global__ __launch_bounds__(256) void xp_kernel(const float* __restrict__ Xg,
                                                 const float* __restrict__ xn,
                                                 float* __restrict__ out,
                                                 const float* __restrict__ ws) {
    __shared__ float X[128 * 65];
    __shared__ float xnew[128];
    __shared__ float red[256];
    __shared__ float tbuf[64];
    __shared__ float xp[128];
    __shared__ float g[64];
    __shared__ float rs[64];
    __shared__ float gmax_s;
    const int b = blockIdx.x, tid = threadIdx.x;
    const float* Xb = Xg + (size_t)b * 8192;

    for (int idx = tid; idx < 2048; idx += 256) {
        float4 v = ((const float4*)Xb)[idx];
        int d = idx >> 4, n = (idx * 4) & 63;
        X[d * 65 + n + 0] = v.x;
        X[d * 65 + n + 1] = v.y;
        X[d * 65 + n + 2] = v.z;
        X[d * 65 + n + 3] = v.w;
    }
    if (tid < 32) {
        float4 v = ((const float4*)(xn + (size_t)b * 128))[tid];
        xnew[tid * 4 + 0] = v.x;
        xnew[tid * 4 + 1] = v.y;
        xnew[tid * 4 + 2] = v.z;
        xnew[tid * 4 + 3] = v.w;
    }
    if (tid >= 192) rs[tid - 192] = ws[(size_t)b * 64 + tid - 192];
    __syncthreads();
    {
        const int n = tid & 63, gi = tid >> 6;
        float p = 0.f;
        for (int d = gi * 32; d < gi * 32 + 32; ++d) p += xnew[d] * X[d * 65 + n];
        red[gi * 64 + n] = p;
    }
    __syncthreads();
    if (tid < 64) tbuf[tid] = red[tid] + red[64 + tid] + red[128 + tid] + red[192 + tid];
    __syncthreads();
    {
        const int d = tid & 127, h = tid >> 7;
        float p = 0.f;
        for (int n = h * 32; n < h * 32 + 32; ++n) p += X[d * 65 + n] * tbuf[n];
        red[h * 128 + d] = p;
    }
    __syncthreads();
    if (tid < 128) {
        float v = red[tid] + red[128 + tid];
        xp[tid] = v;
        out[8388608 + (size_t)b * 128 + tid] = v;
    }
    __syncthreads();
    {
        const int n = tid & 63, gi = tid >> 6;
        float p = 0.f;
        for (int d = gi * 32; d < gi * 32 + 32; ++d) p += xp[d] * X[d * 65 + n];
        red[gi * 64 + n] = p;
    }
    __syncthreads();
    if (tid < 64) {
        float s = red[tid] + red[64 + tid] + red[128 + tid] + red[192 + tid];
        g[tid] = s * s * 0.088388347648318447f;  // 1/sqrt(128)
    }
    __syncthreads();
    if (tid < 64) {
        float m = g[tid];
#pragma unroll
        for (int o = 1; o < 64; o <<= 1) m = fmaxf(m, __shfl_xor(m, o));
        if (tid == 0) gmax_s = m;
    }
    __syncthreads();
    const float gmax = gmax_s;
    const int i = tid >> 2, part = tid & 3;
    const float r = rs[i];
    float e[16];
    float sum = 0.f;
#pragma unroll
    for (int j = 0; j < 16; ++j) {
        e[j] = expf(r * (g[part * 16 + j] - gmax));
        sum += e[j];
    }
    sum += __shfl_xor(sum, 1);
    sum += __shfl_xor(sum, 2);
    const float inv = 1.f / sum;
    float* o = out + (size_t)b * 4096 + i * 64 + part * 16;
#pragma unroll
    for (int j = 0; j < 16; j += 4) {
        float4 v = {e[j] * inv, e[j + 1] * inv, e[j + 2] * inv, e[j + 3] * inv};
        ((float4*)o)[j >> 2] = v;
    }
}

extern "C" void kernel_launch(void* const* d_in, const int* in_sizes, int n_in,
                              void* d_out, int out_size, void* d_ws, size_t ws_size,
                              hipStream_t stream) {
    (void)in_sizes; (void)n_in; (void)out_size; (void)ws_size;
    const float* Ag = (const float*)d_in[0];
    const float* Xg = (const float*)d_in[1];
    const float* xn = (const float*)d_in[2];
    const float* U0 = (const float*)d_in[3];
    const float* V0 = (const float*)d_in[4];
    float* out = (float*)d_out;
    float* ws = (float*)d_ws;

    hipLaunchKernelGGL(nmf_kernel, dim3(2048), dim3(256), 0, stream, Ag, U0, V0, out, ws);
    hipLaunchKernelGGL(xp_kernel, dim3(2048), dim3(256), 0, stream, Xg, xn, out, ws);
}